// Round 11
// baseline (102.013 us; speedup 1.0000x reference)
//
#include <hip/hip_runtime.h>
#include <math.h>

#define H_DIM  4096
#define NE     64
#define TOPK   8
#define KHALF  2048               // K per split
#define WTERM  (NE * H_DIM)       // 262144 elems per packed-W term plane
#define LO_SCALE 2048.0f          // 2^11
#define INV_LO_SCALE (1.0f / 2048.0f)

using f16x8  = __attribute__((ext_vector_type(8))) _Float16;
using hp16x2 = __attribute__((ext_vector_type(2))) __fp16;   // cvt_pkrtz return type
using f32x4  = __attribute__((ext_vector_type(4))) float;

// ---------------- W pre-pack: fp16 2-term split in MFMA B-fragment order ----
// pk[term][kstep][nf][lane][8]: lane = g*16 + (e&15), slot j -> k = kstep*32 + g*8 + j
__global__ __launch_bounds__(256, 1)
void pack_w_kernel(const float* __restrict__ W, _Float16* __restrict__ pk)
{
    int id = blockIdx.x * 256 + threadIdx.x;          // 0 .. 262143
    int e = id >> 12;                                  // / 4096
    int k = id & 4095;
    float f = W[id];
    _Float16 h = (_Float16)f;                          // RNE
    float r = (f - (float)h) * LO_SCALE;               // exact residual, scaled to fp16-normal range
    _Float16 l = (_Float16)r;
    int nf = e >> 4, rr = e & 15;
    int kstep = k >> 5, g = (k >> 3) & 3, j = k & 7;
    int lane = g * 16 + rr;
    size_t idx = (size_t)(kstep * 4 + nf) * 512 + (size_t)lane * 8 + j;
    pk[idx] = h;
    pk[WTERM + idx] = l;
}

// ---------------- main GEMM: partial[kh] = x[:, kh*2048 : +2048] . W^T ------
// block = 2 waves x 32 tokens (64 tokens), one K half; grid = 512 = 2 blocks/CU.
// x converted to f16 hi/lo at staging, stored fragment-order in LDS (144B rows);
// W k-slice shared via LDS. 32 phases x 2 ksteps; raw s_barrier + lgkmcnt(0).
__global__ __launch_bounds__(128, 2)
void moe_logits_mfma(const float* __restrict__ x, const _Float16* __restrict__ pk,
                     float* __restrict__ part0, float* __restrict__ part1)
{
    const int lane = threadIdx.x & 63;
    const int w    = threadIdx.x >> 6;          // wave 0/1
    const int kh   = blockIdx.x & 1;            // K half
    const int tg   = blockIdx.x >> 1;           // 0..255 token group of 64
    const int row0 = tg * 64;
    const int g = lane >> 4, r = lane & 15;
    const int c0 = r * 4;                       // staged col group (0..60)

    // x staging: instr i covers block-token w*32 + i*4 + g, cols c0..c0+4 (dense)
    const float* xg = x + (size_t)(row0 + w * 32 + g) * H_DIM + kh * KHALF + c0;
    // W staging: wave w covers nf = 2w, 2w+1
    const _Float16* wq = pk + (size_t)kh * 131072 + w * 1024 + (size_t)lane * 8;

    __shared__ _Float16 sw[2][2][4096];    // [buf][kip][t*2048+nf*512+lane*8] 32 KB
    __shared__ _Float16 sxh[2][64][72];    // hi plane [buf][tok][col], 144B rows
    __shared__ _Float16 sxl[2][64][72];    // lo plane                (36.9 KB both)

    f32x4 acc[2][4], accL[2][4];
#pragma unroll
    for (int mi = 0; mi < 2; ++mi)
#pragma unroll
        for (int nf = 0; nf < 4; ++nf) { acc[mi][nf] = (f32x4)0.0f; accL[mi][nf] = (f32x4)0.0f; }

    f32x4 xst[8];          // staged x (next phase), 32 f32/lane
    f16x8 wr[2][2][2];     // staged W granules [kip][term][nh]

    // convert xst -> f16 hi/lo, write fragment-order planes of buf_
#define XWRITE(buf_)                                                          \
    do {                                                                      \
        _Pragma("unroll")                                                     \
        for (int i = 0; i < 8; ++i) {                                         \
            const int tok_ = w * 32 + i * 4 + g;                              \
            hp16x2 h0 = __builtin_amdgcn_cvt_pkrtz(xst[i][0], xst[i][1]);     \
            hp16x2 h1 = __builtin_amdgcn_cvt_pkrtz(xst[i][2], xst[i][3]);     \
            hp16x2 l0 = __builtin_amdgcn_cvt_pkrtz(                           \
                (xst[i][0] - (float)h0[0]) * LO_SCALE,                        \
                (xst[i][1] - (float)h0[1]) * LO_SCALE);                       \
            hp16x2 l1 = __builtin_amdgcn_cvt_pkrtz(                           \
                (xst[i][2] - (float)h1[0]) * LO_SCALE,                        \
                (xst[i][3] - (float)h1[1]) * LO_SCALE);                       \
            *(hp16x2*)&sxh[buf_][tok_][c0]     = h0;                          \
            *(hp16x2*)&sxh[buf_][tok_][c0 + 2] = h1;                          \
            *(hp16x2*)&sxl[buf_][tok_][c0]     = l0;                          \
            *(hp16x2*)&sxl[buf_][tok_][c0 + 2] = l1;                          \
        }                                                                     \
    } while (0)

    // ---- prologue: load phase 0, stage into buf 0
#pragma unroll
    for (int kip = 0; kip < 2; ++kip)
#pragma unroll
        for (int t = 0; t < 2; ++t)
#pragma unroll
            for (int nh = 0; nh < 2; ++nh)
                wr[kip][t][nh] = *(const f16x8*)(wq + kip * 2048 + t * WTERM + nh * 512);
#pragma unroll
    for (int i = 0; i < 8; ++i)
        xst[i] = *(const f32x4*)(xg + (size_t)i * 4 * H_DIM);
#pragma unroll
    for (int kip = 0; kip < 2; ++kip)
#pragma unroll
        for (int t = 0; t < 2; ++t)
#pragma unroll
            for (int nh = 0; nh < 2; ++nh)
                *(f16x8*)&sw[0][kip][t * 2048 + (w * 2 + nh) * 512 + lane * 8] = wr[kip][t][nh];
    XWRITE(0);
    asm volatile("s_waitcnt lgkmcnt(0)\n\ts_barrier" ::: "memory");

    // PHASE(b_, LD_, ST_): phase parity b_; LD_: issue P+1 global loads at top;
    // compute 2 ksteps from buf b_; ST_: ds_write P+1 (vmcnt waits land here,
    // ~1 phase after issue); lgkmcnt(0)+barrier.
#define PHASE(b_, LD_, ST_)                                                   \
    do {                                                                      \
        if (LD_) {                                                            \
            _Pragma("unroll")                                                 \
            for (int kip = 0; kip < 2; ++kip)                                 \
                _Pragma("unroll")                                             \
                for (int t = 0; t < 2; ++t)                                   \
                    _Pragma("unroll")                                         \
                    for (int nh = 0; nh < 2; ++nh)                            \
                        wr[kip][t][nh] = *(const f16x8*)(wq + (b_) * 4096     \
                            + 4096 + kip * 2048 + t * WTERM + nh * 512);      \
            _Pragma("unroll")                                                 \
            for (int i = 0; i < 8; ++i)                                       \
                xst[i] = *(const f32x4*)(xg + (size_t)i * 4 * H_DIM           \
                                         + (b_) * 64 + 64);                   \
        }                                                                     \
        _Pragma("unroll")                                                     \
        for (int kip = 0; kip < 2; ++kip) {                                   \
            f16x8 wa[2][4];                                                   \
            _Pragma("unroll")                                                 \
            for (int t = 0; t < 2; ++t)                                       \
                _Pragma("unroll")                                             \
                for (int nf = 0; nf < 4; ++nf)                                \
                    wa[t][nf] = *(const f16x8*)                               \
                        &sw[b_][kip][t * 2048 + nf * 512 + lane * 8];         \
            f16x8 a1[2], a2[2];                                               \
            _Pragma("unroll")                                                 \
            for (int mi = 0; mi < 2; ++mi) {                                  \
                a1[mi] = *(const f16x8*)                                      \
                    &sxh[b_][w * 32 + mi * 16 + r][kip * 32 + g * 8];         \
                a2[mi] = *(const f16x8*)                                      \
                    &sxl[b_][w * 32 + mi * 16 + r][kip * 32 + g * 8];         \
            }                                                                 \
            _Pragma("unroll")                                                 \
            for (int mi = 0; mi < 2; ++mi)                                    \
                _Pragma("unroll")                                             \
                for (int nf = 0; nf < 4; ++nf) {                              \
                    acc[mi][nf]  = __builtin_amdgcn_mfma_f32_16x16x32_f16(    \
                        a1[mi], wa[0][nf], acc[mi][nf], 0, 0, 0);             \
                    accL[mi][nf] = __builtin_amdgcn_mfma_f32_16x16x32_f16(    \
                        a1[mi], wa[1][nf], accL[mi][nf], 0, 0, 0);            \
                    accL[mi][nf] = __builtin_amdgcn_mfma_f32_16x16x32_f16(    \
                        a2[mi], wa[0][nf], accL[mi][nf], 0, 0, 0);            \
                }                                                             \
        }                                                                     \
        if (ST_) {                                                            \
            _Pragma("unroll")                                                 \
            for (int kip = 0; kip < 2; ++kip)                                 \
                _Pragma("unroll")                                             \
                for (int t = 0; t < 2; ++t)                                   \
                    _Pragma("unroll")                                         \
                    for (int nh = 0; nh < 2; ++nh)                            \
                        *(f16x8*)&sw[(b_) ^ 1][kip][t * 2048                  \
                            + (w * 2 + nh) * 512 + lane * 8] = wr[kip][t][nh];\
            XWRITE((b_) ^ 1);                                                 \
        }                                                                     \
        asm volatile("s_waitcnt lgkmcnt(0)\n\ts_barrier" ::: "memory");       \
    } while (0)

    // phases 0..29 (15 pairs), steady state
#pragma unroll 1
    for (int it = 0; it < 15; ++it) {
        PHASE(0, 1, 1);
        PHASE(1, 1, 1);
        xg += 128;
        wq += 8192;
    }
    PHASE(0, 1, 1);    // phase 30: loads+stages phase 31
    PHASE(1, 0, 0);    // phase 31: compute only

#undef PHASE
#undef XWRITE

    // store partial tile: D row (token) = g*4+q, col (expert) = nf*16+r
    float* outp = kh == 0 ? part0 : part1;
#pragma unroll
    for (int mi = 0; mi < 2; ++mi)
#pragma unroll
        for (int nf = 0; nf < 4; ++nf)
#pragma unroll
            for (int q = 0; q < 4; ++q) {
                float v = acc[mi][nf][q] + accL[mi][nf][q] * INV_LO_SCALE;
                outp[(size_t)(row0 + w * 32 + mi * 16 + g * 4 + q) * NE + nf * 16 + r] = v;
            }
}

// ---------------- router: sum partials, softmax + top-8 + L1 renorm ---------
// NOTE: scores aliases p0 and logits aliases p1 — each wave reads only its own
// token row before writing it; rows are wave-exclusive, so this is race-free.
__global__ __launch_bounds__(256, 1)
void router_kernel(const float* p0, const float* p1, float* scores,
                   float* logits, float* wts, float* inds, int N)
{
    const int token = blockIdx.x * 4 + (threadIdx.x >> 6);
    const int lane  = threadIdx.x & 63;
    if (token >= N) return;

    const float l = p0[(size_t)token * NE + lane] + p1[(size_t)token * NE + lane];

    float m = l;
#pragma unroll
    for (int off = 32; off >= 1; off >>= 1)
        m = fmaxf(m, __shfl_xor(m, off, 64));
    const float p = expf(l - m);
    float s = p;
#pragma unroll
    for (int off = 32; off >= 1; off >>= 1)
        s += __shfl_xor(s, off, 64);
    const float sc = p / s;

    scores[(size_t)token * NE + lane] = sc;
    logits[(size_t)token * NE + lane] = l;

    float cur = sc;
    float tv[TOPK];
    int   ti[TOPK];
    float sum8 = 0.0f;
#pragma unroll
    for (int k = 0; k < TOPK; ++k) {
        float v = cur; int i = lane;
#pragma unroll
        for (int off = 32; off >= 1; off >>= 1) {
            float ov = __shfl_xor(v, off, 64);
            int   oi = __shfl_xor(i, off, 64);
            if (ov > v || (ov == v && oi < i)) { v = ov; i = oi; }
        }
        tv[k] = v; ti[k] = i;
        sum8 += v;
        if (lane == i) cur = -1.0f;   // scores > 0, so -1 masks
    }

    if (lane == 0) {
#pragma unroll
        for (int k = 0; k < TOPK; ++k) {
            wts[(size_t)token * TOPK + k]  = tv[k] / sum8;
            inds[(size_t)token * TOPK + k] = (float)ti[k];
        }
    }
}

extern "C" void kernel_launch(void* const* d_in, const int* in_sizes, int n_in,
                              void* d_out, int out_size, void* d_ws, size_t ws_size,
                              hipStream_t stream)
{
    const float* x = (const float*)d_in[0];
    const float* W = (const float*)d_in[1];
    const int N = in_sizes[0] / H_DIM;   // 16384

    float* out    = (float*)d_out;
    float* scores = out;                          // [N,64]  (doubles as partial kh=0)
    float* logits = out + (size_t)N * NE;         // [N,64]  (doubles as partial kh=1)
    float* wts    = out + (size_t)2 * N * NE;     // [N,8]
    float* inds   = wts + (size_t)N * TOPK;       // [N,8] as float

    _Float16* pk = (_Float16*)d_ws;               // 2 * 262144 * 2B = 1 MB

    pack_w_kernel<<<(NE * H_DIM) / 256, 256, 0, stream>>>(W, pk);
    moe_logits_mfma<<<(N / 64) * 2, 128, 0, stream>>>(x, pk, scores, logits);
    router_kernel<<<(N + 3) / 4, 256, 0, stream>>>(scores, logits, scores, logits,
                                                   wts, inds, N);
}

// Round 12
// 89.286 us; speedup vs baseline: 1.1425x; 1.1425x over previous
//
#include <hip/hip_runtime.h>
#include <math.h>

#define H_DIM  4096
#define NE     64
#define TOPK   8
#define KHALF  2048               // K per split
#define WTERM  (NE * H_DIM)       // 262144 elems per packed-W term plane
#define LO_SCALE 2048.0f          // 2^11
#define INV_LO_SCALE (1.0f / 2048.0f)

using f16x8  = __attribute__((ext_vector_type(8))) _Float16;
using hp16x2 = __attribute__((ext_vector_type(2))) __fp16;   // cvt_pkrtz return type
using f32x4  = __attribute__((ext_vector_type(4))) float;

__device__ __forceinline__ unsigned pk2u(hp16x2 v) {
    union { hp16x2 h; unsigned u; } c; c.h = v; return c.u;
}

// ---------------- W pre-pack: fp16 2-term split in MFMA B-fragment order ----
// pk[term][kstep][nf][lane][8]: lane = g*16 + (e&15), slot j -> k = kstep*32 + g*8 + j
__global__ __launch_bounds__(256, 1)
void pack_w_kernel(const float* __restrict__ W, _Float16* __restrict__ pk)
{
    int id = blockIdx.x * 256 + threadIdx.x;          // 0 .. 262143
    int e = id >> 12;                                  // / 4096
    int k = id & 4095;
    float f = W[id];
    _Float16 h = (_Float16)f;                          // RNE
    float r = (f - (float)h) * LO_SCALE;               // exact residual, scaled to fp16-normal range
    _Float16 l = (_Float16)r;
    int nf = e >> 4, rr = e & 15;
    int kstep = k >> 5, g = (k >> 3) & 3, j = k & 7;
    int lane = g * 16 + rr;
    size_t idx = (size_t)(kstep * 4 + nf) * 512 + (size_t)lane * 8 + j;
    pk[idx] = h;
    pk[WTERM + idx] = l;
}

// ---------------- main GEMM: partial[kh] = x[:, kh*2048 : +2048] . W^T ------
// block = 4 waves (256 thr), 64 tokens; wave = 32 tok (tw) x 32 exp (ew).
// grid = 512 (256 tg x 2 kh) -> 2 blocks/CU, 8 waves/CU = 2 waves/SIMD.
// x staged as f16 hi/lo fragment planes (128B rows + 16B-slot XOR swizzle);
// W k-slice in LDS. 32 phases x 2 ksteps; raw s_barrier + lgkmcnt(0).
__global__ __launch_bounds__(256, 2)
void moe_logits_mfma(const float* __restrict__ x, const _Float16* __restrict__ pk,
                     float* __restrict__ part0, float* __restrict__ part1)
{
    const int lane = threadIdx.x & 63;
    const int wid  = threadIdx.x >> 6;          // 0..3
    const int kh   = blockIdx.x & 1;            // K half
    const int tg   = blockIdx.x >> 1;           // token group of 64
    const int row0 = tg * 64;
    const int tw = wid >> 1, ew = wid & 1;      // token / expert half
    const int g = lane >> 4, r = lane & 15;

    // x staging: instr i covers tok wid*16 + i*4 + g, cols r*4..r*4+3 (dense 256B rows)
    const float* xg = x + (size_t)(row0 + wid * 16 + g) * H_DIM + kh * KHALF + r * 4;
    // W staging: wave wid stages nf = wid
    const _Float16* wq = pk + (size_t)kh * 131072 + wid * 512 + (size_t)lane * 8;

    __shared__ _Float16 sw[2][2][4096];   // [buf][kip][t*2048 + nf*512 + lane*8]  32 KB
    __shared__ _Float16 sxh[2][4096];     // [buf][tok*64 + swz(kslot)*8 + j]      16 KB
    __shared__ _Float16 sxl[2][4096];     //                                       16 KB

    f32x4 acc[2][2], accL[2][2];
#pragma unroll
    for (int mi = 0; mi < 2; ++mi)
#pragma unroll
        for (int n = 0; n < 2; ++n) { acc[mi][n] = (f32x4)0.0f; accL[mi][n] = (f32x4)0.0f; }

    f32x4 xst[4];          // staged x (next phase): 4 rows x 4 cols
    f16x8 wst[2][2];       // staged W granules [kip][term]

    // convert xst -> f16 hi/lo, write swizzled fragment planes of buf_
#define XWRITE(buf_)                                                          \
    do {                                                                      \
        _Pragma("unroll")                                                     \
        for (int i = 0; i < 4; ++i) {                                         \
            const int tok_ = wid * 16 + i * 4 + g;                            \
            hp16x2 h0 = __builtin_amdgcn_cvt_pkrtz(xst[i][0], xst[i][1]);     \
            hp16x2 h1 = __builtin_amdgcn_cvt_pkrtz(xst[i][2], xst[i][3]);     \
            hp16x2 l0 = __builtin_amdgcn_cvt_pkrtz(                           \
                (xst[i][0] - (float)h0[0]) * LO_SCALE,                        \
                (xst[i][1] - (float)h0[1]) * LO_SCALE);                       \
            hp16x2 l1 = __builtin_amdgcn_cvt_pkrtz(                           \
                (xst[i][2] - (float)h1[0]) * LO_SCALE,                        \
                (xst[i][3] - (float)h1[1]) * LO_SCALE);                       \
            const int woff = tok_ * 64 + (((r >> 1) ^ (tok_ & 7)) << 3)       \
                             + (r & 1) * 4;                                   \
            uint2 uh; uh.x = pk2u(h0); uh.y = pk2u(h1);                       \
            uint2 ul; ul.x = pk2u(l0); ul.y = pk2u(l1);                       \
            *(uint2*)&sxh[buf_][woff] = uh;                                   \
            *(uint2*)&sxl[buf_][woff] = ul;                                   \
        }                                                                     \
    } while (0)

    // ---- prologue: load phase 0, stage into buf 0
#pragma unroll
    for (int kip = 0; kip < 2; ++kip)
#pragma unroll
        for (int t = 0; t < 2; ++t)
            wst[kip][t] = *(const f16x8*)(wq + kip * 2048 + t * WTERM);
#pragma unroll
    for (int i = 0; i < 4; ++i)
        xst[i] = *(const f32x4*)(xg + (size_t)i * 4 * H_DIM);
#pragma unroll
    for (int kip = 0; kip < 2; ++kip)
#pragma unroll
        for (int t = 0; t < 2; ++t)
            *(f16x8*)&sw[0][kip][t * 2048 + wid * 512 + lane * 8] = wst[kip][t];
    XWRITE(0);
    asm volatile("s_waitcnt lgkmcnt(0)\n\ts_barrier" ::: "memory");

    // PHASE(b_, LD_, ST_): LD_: issue P+1 globals at top; compute buf b_;
    // ST_: ds_write P+1 (vmcnt waits land here, ~1 phase after issue); barrier.
#define PHASE(b_, LD_, ST_)                                                   \
    do {                                                                      \
        if (LD_) {                                                            \
            _Pragma("unroll")                                                 \
            for (int kip = 0; kip < 2; ++kip)                                 \
                _Pragma("unroll")                                             \
                for (int t = 0; t < 2; ++t)                                   \
                    wst[kip][t] = *(const f16x8*)(wq + (b_) * 4096 + 4096     \
                                                  + kip * 2048 + t * WTERM);  \
            _Pragma("unroll")                                                 \
            for (int i = 0; i < 4; ++i)                                       \
                xst[i] = *(const f32x4*)(xg + (size_t)i * 4 * H_DIM           \
                                         + (b_) * 64 + 64);                   \
        }                                                                     \
        _Pragma("unroll")                                                     \
        for (int kip = 0; kip < 2; ++kip) {                                   \
            f16x8 wb[2][2];                                                   \
            _Pragma("unroll")                                                 \
            for (int t = 0; t < 2; ++t)                                       \
                _Pragma("unroll")                                             \
                for (int n = 0; n < 2; ++n)                                   \
                    wb[t][n] = *(const f16x8*)                                \
                        &sw[b_][kip][t * 2048 + (ew * 2 + n) * 512 + lane * 8];\
            f16x8 a1[2], a2[2];                                               \
            _Pragma("unroll")                                                 \
            for (int mi = 0; mi < 2; ++mi) {                                  \
                const int tok_ = tw * 32 + mi * 16 + r;                       \
                const int aoff = tok_ * 64                                    \
                                 + (((kip * 4 + g) ^ (tok_ & 7)) << 3);       \
                a1[mi] = *(const f16x8*)&sxh[b_][aoff];                       \
                a2[mi] = *(const f16x8*)&sxl[b_][aoff];                       \
            }                                                                 \
            _Pragma("unroll")                                                 \
            for (int mi = 0; mi < 2; ++mi)                                    \
                _Pragma("unroll")                                             \
                for (int n = 0; n < 2; ++n) {                                 \
                    acc[mi][n]  = __builtin_amdgcn_mfma_f32_16x16x32_f16(     \
                        a1[mi], wb[0][n], acc[mi][n], 0, 0, 0);               \
                    accL[mi][n] = __builtin_amdgcn_mfma_f32_16x16x32_f16(     \
                        a1[mi], wb[1][n], accL[mi][n], 0, 0, 0);              \
                    accL[mi][n] = __builtin_amdgcn_mfma_f32_16x16x32_f16(     \
                        a2[mi], wb[0][n], accL[mi][n], 0, 0, 0);              \
                }                                                             \
        }                                                                     \
        if (ST_) {                                                            \
            _Pragma("unroll")                                                 \
            for (int kip = 0; kip < 2; ++kip)                                 \
                _Pragma("unroll")                                             \
                for (int t = 0; t < 2; ++t)                                   \
                    *(f16x8*)&sw[(b_) ^ 1][kip][t * 2048 + wid * 512          \
                                               + lane * 8] = wst[kip][t];     \
            XWRITE((b_) ^ 1);                                                 \
        }                                                                     \
        asm volatile("s_waitcnt lgkmcnt(0)\n\ts_barrier" ::: "memory");       \
    } while (0)

    // phases 0..29 (15 pairs), steady state
#pragma unroll 1
    for (int it = 0; it < 15; ++it) {
        PHASE(0, 1, 1);
        PHASE(1, 1, 1);
        xg += 128;
        wq += 8192;
    }
    PHASE(0, 1, 1);    // phase 30: loads+stages phase 31
    PHASE(1, 0, 0);    // phase 31: compute only

#undef PHASE
#undef XWRITE

    // store partial tile: D row (token) = g*4+q, col (expert) = n*16+r
    float* outp = kh == 0 ? part0 : part1;
#pragma unroll
    for (int mi = 0; mi < 2; ++mi)
#pragma unroll
        for (int n = 0; n < 2; ++n)
#pragma unroll
            for (int q = 0; q < 4; ++q) {
                float v = acc[mi][n][q] + accL[mi][n][q] * INV_LO_SCALE;
                outp[(size_t)(row0 + tw * 32 + mi * 16 + g * 4 + q) * NE
                     + ew * 32 + n * 16 + r] = v;
            }
}

// ---------------- router: sum partials, softmax + top-8 + L1 renorm ---------
// NOTE: scores aliases p0 and logits aliases p1 — each wave reads only its own
// token row before writing it; rows are wave-exclusive, so this is race-free.
__global__ __launch_bounds__(256, 1)
void router_kernel(const float* p0, const float* p1, float* scores,
                   float* logits, float* wts, float* inds, int N)
{
    const int token = blockIdx.x * 4 + (threadIdx.x >> 6);
    const int lane  = threadIdx.x & 63;
    if (token >= N) return;

    const float l = p0[(size_t)token * NE + lane] + p1[(size_t)token * NE + lane];

    float m = l;
#pragma unroll
    for (int off = 32; off >= 1; off >>= 1)
        m = fmaxf(m, __shfl_xor(m, off, 64));
    const float p = expf(l - m);
    float s = p;
#pragma unroll
    for (int off = 32; off >= 1; off >>= 1)
        s += __shfl_xor(s, off, 64);
    const float sc = p / s;

    scores[(size_t)token * NE + lane] = sc;
    logits[(size_t)token * NE + lane] = l;

    float cur = sc;
    float tv[TOPK];
    int   ti[TOPK];
    float sum8 = 0.0f;
#pragma unroll
    for (int k = 0; k < TOPK; ++k) {
        float v = cur; int i = lane;
#pragma unroll
        for (int off = 32; off >= 1; off >>= 1) {
            float ov = __shfl_xor(v, off, 64);
            int   oi = __shfl_xor(i, off, 64);
            if (ov > v || (ov == v && oi < i)) { v = ov; i = oi; }
        }
        tv[k] = v; ti[k] = i;
        sum8 += v;
        if (lane == i) cur = -1.0f;   // scores > 0, so -1 masks
    }

    if (lane == 0) {
#pragma unroll
        for (int k = 0; k < TOPK; ++k) {
            wts[(size_t)token * TOPK + k]  = tv[k] / sum8;
            inds[(size_t)token * TOPK + k] = (float)ti[k];
        }
    }
}

extern "C" void kernel_launch(void* const* d_in, const int* in_sizes, int n_in,
                              void* d_out, int out_size, void* d_ws, size_t ws_size,
                              hipStream_t stream)
{
    const float* x = (const float*)d_in[0];
    const float* W = (const float*)d_in[1];
    const int N = in_sizes[0] / H_DIM;   // 16384

    float* out    = (float*)d_out;
    float* scores = out;                          // [N,64]  (doubles as partial kh=0)
    float* logits = out + (size_t)N * NE;         // [N,64]  (doubles as partial kh=1)
    float* wts    = out + (size_t)2 * N * NE;     // [N,8]
    float* inds   = wts + (size_t)N * TOPK;       // [N,8] as float

    _Float16* pk = (_Float16*)d_ws;               // 2 * 262144 * 2B = 1 MB

    pack_w_kernel<<<(NE * H_DIM) / 256, 256, 0, stream>>>(W, pk);
    moe_logits_mfma<<<(N / 64) * 2, 256, 0, stream>>>(x, pk, scores, logits);
    router_kernel<<<(N + 3) / 4, 256, 0, stream>>>(scores, logits, scores, logits,
                                                   wts, inds, N);
}

// Round 13
// 82.981 us; speedup vs baseline: 1.2293x; 1.0760x over previous
//
#include <hip/hip_runtime.h>
#include <math.h>

#define H_DIM  4096
#define NE     64
#define TOPK   8
#define KHALF  2048               // K per split
#define WTERM  (NE * H_DIM)       // 262144 elems per packed-W term plane
#define LO_SCALE 2048.0f          // 2^11
#define INV_LO_SCALE (1.0f / 2048.0f)

using f16x8  = __attribute__((ext_vector_type(8))) _Float16;
using hp16x2 = __attribute__((ext_vector_type(2))) __fp16;   // cvt_pkrtz return type
using f32x4  = __attribute__((ext_vector_type(4))) float;

// ---------------- W pre-pack: fp16 2-term split in MFMA B-fragment order ----
// pk[term][kstep][nf][lane][8]: lane = g*16 + (e&15), slot j -> k = kstep*32 + g*8 + j
__global__ __launch_bounds__(256, 1)
void pack_w_kernel(const float* __restrict__ W, _Float16* __restrict__ pk)
{
    int id = blockIdx.x * 256 + threadIdx.x;          // 0 .. 262143
    int e = id >> 12;                                  // / 4096
    int k = id & 4095;
    float f = W[id];
    _Float16 h = (_Float16)f;                          // RNE
    float r = (f - (float)h) * LO_SCALE;               // exact residual, scaled to fp16-normal range
    _Float16 l = (_Float16)r;
    int nf = e >> 4, rr = e & 15;
    int kstep = k >> 5, g = (k >> 3) & 3, j = k & 7;
    int lane = g * 16 + rr;
    size_t idx = (size_t)(kstep * 4 + nf) * 512 + (size_t)lane * 8 + j;
    pk[idx] = h;
    pk[WTERM + idx] = l;
}

// ---------------- main GEMM: partial[kh] = x[:, kh*2048 : +2048] . W^T ------
// block = 4 waves x 16 tokens (64 tokens), one K half; W k-slice shared via LDS;
// x staged coalesced -> transposed pad-17 LDS (per-wave private).
// 32 phases x 2 ksteps; raw s_barrier + lgkmcnt(0); counted vmcnt only.
// NEW vs 80.3 baseline: x prefetch issued in BATCHED PAIRS on even phases
// (adjacent 256B chunks per row back-to-back -> DRAM page-hit friendly).
__global__ __launch_bounds__(256, 2)
void moe_logits_mfma(const float* __restrict__ x, const _Float16* __restrict__ pk,
                     float* __restrict__ part0, float* __restrict__ part1)
{
    const int lane = threadIdx.x & 63;
    const int wid  = threadIdx.x >> 6;          // 0..3 token sub-group / stage quarter
    const int kh   = blockIdx.x & 1;            // K half
    const int tg   = blockIdx.x >> 1;           // 0..255 token group of 64
    const int row0 = tg * 64 + wid * 16;
    const int g = lane >> 4, r = lane & 15;

    // coalesced x staging base: instr i covers rows i*4+(lane>>4), 16B at col (lane&15)*4
    const float* xg = x + (size_t)(row0 + (lane >> 4)) * H_DIM + kh * KHALF + (lane & 15) * 4;
    // W staging source: this wave's quarter of each per-kstep slice
    const _Float16* wq = pk + (size_t)(kh * 64) * 2048 + wid * 512 + (size_t)lane * 8;

    __shared__ _Float16 sw[2][2][4096];   // [buf][kip][t*2048+nf*512+lane*8] : 32 KB
    __shared__ float    sx[2][4][1088];   // [buf][wave][col*17 + row]        : 34.8 KB
    const int lbase = wid * 512 + lane * 8;
    const int c0 = (lane & 15) * 4;       // staged col group
    const int rq = lane >> 4;             // staged row-in-quad

    f32x4 acc[4], accL[4];
#pragma unroll
    for (int nf = 0; nf < 4; ++nf) { acc[nf] = (f32x4)0.0f; accL[nf] = (f32x4)0.0f; }

    f32x4 xst[2][4];       // [phase-buf][row-quad]
    f16x8 wr[2][2][2];     // [phase-buf][kip][term]  W for phase P+1 in wr[(P+1)&1]

    // ---- prologue: regs <- x/W of phases 0,1; LDS buf0 <- phase 0
#pragma unroll
    for (int i = 0; i < 4; ++i) {
        xst[0][i] = *(const f32x4*)(xg + (size_t)i * 4 * H_DIM);
        xst[1][i] = *(const f32x4*)(xg + (size_t)i * 4 * H_DIM + 64);
    }
#pragma unroll
    for (int kip = 0; kip < 2; ++kip)
#pragma unroll
        for (int t = 0; t < 2; ++t) {
            wr[0][kip][t] = *(const f16x8*)(wq + kip * 2048 + t * WTERM);
            wr[1][kip][t] = *(const f16x8*)(wq + 4096 + kip * 2048 + t * WTERM);
        }
#pragma unroll
    for (int kip = 0; kip < 2; ++kip)
#pragma unroll
        for (int t = 0; t < 2; ++t)
            *(f16x8*)&sw[0][kip][t * 2048 + lbase] = wr[0][kip][t];
#pragma unroll
    for (int i = 0; i < 4; ++i)
#pragma unroll
        for (int j = 0; j < 4; ++j)
            sx[0][wid][(c0 + j) * 17 + i * 4 + rq] = xst[0][i][j];
    asm volatile("s_waitcnt lgkmcnt(0)\n\ts_barrier" ::: "memory");

    // PHASE(b_, DSW_, PFW_, PFX_):
    //  b_: phase parity; DSW_: ds_write regs of phase P+1 into LDS buf b^1
    //  PFW_: issue W(P+2) -> wr[b_]
    //  PFX_==2 (even phases only): issue x(P+2)->xst[b_] AND x(P+3)->xst[b_^1]
    //  (xst[b_^1] is dead after DSW_ consumed it at the top of this phase)
#define PHASE(b_, DSW_, PFW_, PFX_)                                            \
    do {                                                                       \
        if (DSW_) {                                                            \
            _Pragma("unroll")                                                  \
            for (int kip = 0; kip < 2; ++kip)                                  \
                _Pragma("unroll")                                              \
                for (int t = 0; t < 2; ++t)                                    \
                    *(f16x8*)&sw[(b_) ^ 1][kip][t * 2048 + lbase] =            \
                        wr[(b_) ^ 1][kip][t];                                  \
            _Pragma("unroll")                                                  \
            for (int i = 0; i < 4; ++i)                                        \
                _Pragma("unroll")                                              \
                for (int j = 0; j < 4; ++j)                                    \
                    sx[(b_) ^ 1][wid][(c0 + j) * 17 + i * 4 + rq] =            \
                        xst[(b_) ^ 1][i][j];                                   \
        }                                                                      \
        if (PFW_) {                                                            \
            _Pragma("unroll")                                                  \
            for (int kip = 0; kip < 2; ++kip)                                  \
                _Pragma("unroll")                                              \
                for (int t = 0; t < 2; ++t)                                    \
                    wr[b_][kip][t] = *(const f16x8*)(wq + (b_) * 4096 + 8192   \
                                                     + kip * 2048 + t * WTERM);\
        }                                                                      \
        if ((PFX_) == 2) {                                                     \
            _Pragma("unroll")                                                  \
            for (int i = 0; i < 4; ++i)                                        \
                xst[b_][i] = *(const f32x4*)(xg + (size_t)i * 4 * H_DIM + 128);\
            _Pragma("unroll")                                                  \
            for (int i = 0; i < 4; ++i)                                        \
                xst[(b_) ^ 1][i] = *(const f32x4*)(xg + (size_t)i * 4 * H_DIM  \
                                                   + 192);                     \
        }                                                                      \
        _Pragma("unroll")                                                      \
        for (int kip = 0; kip < 2; ++kip) {                                    \
            f16x8 wa[2][4];                                                    \
            _Pragma("unroll")                                                  \
            for (int t = 0; t < 2; ++t)                                        \
                _Pragma("unroll")                                              \
                for (int nf = 0; nf < 4; ++nf)                                 \
                    wa[t][nf] = *(const f16x8*)                                \
                        &sw[b_][kip][t * 2048 + nf * 512 + lane * 8];          \
            float xv[8];                                                       \
            _Pragma("unroll")                                                  \
            for (int j = 0; j < 8; ++j)                                        \
                xv[j] = sx[b_][wid][(kip * 32 + g * 8 + j) * 17 + r];          \
            f16x8 a1, a2;                                                      \
            _Pragma("unroll")                                                  \
            for (int j = 0; j < 8; j += 2) {                                   \
                float v0 = xv[j], v1 = xv[j + 1];                              \
                hp16x2 hp = __builtin_amdgcn_cvt_pkrtz(v0, v1);                \
                float r0 = (v0 - (float)hp[0]) * LO_SCALE;                     \
                float r1 = (v1 - (float)hp[1]) * LO_SCALE;                     \
                hp16x2 lp = __builtin_amdgcn_cvt_pkrtz(r0, r1);                \
                a1[j]     = (_Float16)hp[0];                                   \
                a1[j + 1] = (_Float16)hp[1];                                   \
                a2[j]     = (_Float16)lp[0];                                   \
                a2[j + 1] = (_Float16)lp[1];                                   \
            }                                                                  \
            _Pragma("unroll")                                                  \
            for (int nf = 0; nf < 4; ++nf) {                                   \
                acc[nf]  = __builtin_amdgcn_mfma_f32_16x16x32_f16(             \
                               a1, wa[0][nf], acc[nf], 0, 0, 0);               \
                accL[nf] = __builtin_amdgcn_mfma_f32_16x16x32_f16(             \
                               a1, wa[1][nf], accL[nf], 0, 0, 0);              \
                accL[nf] = __builtin_amdgcn_mfma_f32_16x16x32_f16(             \
                               a2, wa[0][nf], accL[nf], 0, 0, 0);              \
            }                                                                  \
        }                                                                      \
        asm volatile("s_waitcnt lgkmcnt(0)\n\ts_barrier" ::: "memory");        \
    } while (0)

    // phases 0..29 (15 pairs); even phases dual-issue x(P+2),x(P+3)
#pragma unroll 1
    for (int it = 0; it < 15; ++it) {
        PHASE(0, 1, 1, 2);
        PHASE(1, 1, 1, 0);
        xg += 128;
        wq += 8192;
    }
    PHASE(0, 1, 0, 0);    // phase 30: stage phase-31 regs, no more prefetch
    PHASE(1, 0, 0, 0);    // phase 31: compute only

#undef PHASE

    // store partial tile: D row (token) = g*4+q, col (expert) = nf*16+r
    float* outp = kh == 0 ? part0 : part1;
#pragma unroll
    for (int nf = 0; nf < 4; ++nf)
#pragma unroll
        for (int q = 0; q < 4; ++q) {
            float v = acc[nf][q] + accL[nf][q] * INV_LO_SCALE;
            outp[(size_t)(row0 + g * 4 + q) * NE + nf * 16 + r] = v;
        }
}

// ---------------- router: sum partials, softmax + top-8 + L1 renorm ---------
// NOTE: scores aliases p0 and logits aliases p1 — each wave reads only its own
// token row before writing it; rows are wave-exclusive, so this is race-free.
__global__ __launch_bounds__(256, 1)
void router_kernel(const float* p0, const float* p1, float* scores,
                   float* logits, float* wts, float* inds, int N)
{
    const int token = blockIdx.x * 4 + (threadIdx.x >> 6);
    const int lane  = threadIdx.x & 63;
    if (token >= N) return;

    const float l = p0[(size_t)token * NE + lane] + p1[(size_t)token * NE + lane];

    float m = l;
#pragma unroll
    for (int off = 32; off >= 1; off >>= 1)
        m = fmaxf(m, __shfl_xor(m, off, 64));
    const float p = expf(l - m);
    float s = p;
#pragma unroll
    for (int off = 32; off >= 1; off >>= 1)
        s += __shfl_xor(s, off, 64);
    const float sc = p / s;

    scores[(size_t)token * NE + lane] = sc;
    logits[(size_t)token * NE + lane] = l;

    float cur = sc;
    float tv[TOPK];
    int   ti[TOPK];
    float sum8 = 0.0f;
#pragma unroll
    for (int k = 0; k < TOPK; ++k) {
        float v = cur; int i = lane;
#pragma unroll
        for (int off = 32; off >= 1; off >>= 1) {
            float ov = __shfl_xor(v, off, 64);
            int   oi = __shfl_xor(i, off, 64);
            if (ov > v || (ov == v && oi < i)) { v = ov; i = oi; }
        }
        tv[k] = v; ti[k] = i;
        sum8 += v;
        if (lane == i) cur = -1.0f;   // scores > 0, so -1 masks
    }

    if (lane == 0) {
#pragma unroll
        for (int k = 0; k < TOPK; ++k) {
            wts[(size_t)token * TOPK + k]  = tv[k] / sum8;
            inds[(size_t)token * TOPK + k] = (float)ti[k];
        }
    }
}

extern "C" void kernel_launch(void* const* d_in, const int* in_sizes, int n_in,
                              void* d_out, int out_size, void* d_ws, size_t ws_size,
                              hipStream_t stream)
{
    const float* x = (const float*)d_in[0];
    const float* W = (const float*)d_in[1];
    const int N = in_sizes[0] / H_DIM;   // 16384

    float* out    = (float*)d_out;
    float* scores = out;                          // [N,64]  (doubles as partial kh=0)
    float* logits = out + (size_t)N * NE;         // [N,64]  (doubles as partial kh=1)
    float* wts    = out + (size_t)2 * N * NE;     // [N,8]
    float* inds   = wts + (size_t)N * TOPK;       // [N,8] as float

    _Float16* pk = (_Float16*)d_ws;               // 2 * 262144 * 2B = 1 MB

    pack_w_kernel<<<(NE * H_DIM) / 256, 256, 0, stream>>>(W, pk);
    moe_logits_mfma<<<(N / 64) * 2, 256, 0, stream>>>(x, pk, scores, logits);
    router_kernel<<<(N + 3) / 4, 256, 0, stream>>>(scores, logits, scores, logits,
                                                   wts, inds, N);
}

// Round 14
// 72.893 us; speedup vs baseline: 1.3995x; 1.1384x over previous
//
#include <hip/hip_runtime.h>
#include <math.h>

#define H_DIM  4096
#define NE     64
#define TOPK   8
#define KHALF  2048               // K per split
#define WTERM  (NE * H_DIM)       // 262144 elems per packed-W term plane
#define LO_SCALE 2048.0f          // 2^11
#define INV_LO_SCALE (1.0f / 2048.0f)

using f16x8  = __attribute__((ext_vector_type(8))) _Float16;
using hp16x2 = __attribute__((ext_vector_type(2))) __fp16;   // cvt_pkrtz return type
using f32x4  = __attribute__((ext_vector_type(4))) float;

// ---------------- W pre-pack: fp16 2-term split in MFMA B-fragment order ----
// pk[term][kstep][nf][lane][8]: lane = g*16 + (e&15), slot j -> k = kstep*32 + g*8 + j
__global__ __launch_bounds__(256, 1)
void pack_w_kernel(const float* __restrict__ W, _Float16* __restrict__ pk)
{
    int id = blockIdx.x * 256 + threadIdx.x;          // 0 .. 262143
    int e = id >> 12;                                  // / 4096
    int k = id & 4095;
    float f = W[id];
    _Float16 h = (_Float16)f;                          // RNE
    float r = (f - (float)h) * LO_SCALE;               // exact residual, scaled to fp16-normal range
    _Float16 l = (_Float16)r;
    int nf = e >> 4, rr = e & 15;
    int kstep = k >> 5, g = (k >> 3) & 3, j = k & 7;
    int lane = g * 16 + rr;
    size_t idx = (size_t)(kstep * 4 + nf) * 512 + (size_t)lane * 8 + j;
    pk[idx] = h;
    pk[WTERM + idx] = l;
}

// ---------------- main GEMM: partial[kh] = x[:, kh*2048 : +2048] . W^T ------
// (champion 80.3 µs structure, verbatim)
// block = 4 waves x 16 tokens (64 tokens), one K half; W k-slice shared via LDS;
// x staged coalesced -> transposed pad-17 LDS (per-wave private).
// 32 phases x 2 ksteps; raw s_barrier + lgkmcnt(0); counted vmcnt only.
__global__ __launch_bounds__(256, 2)
void moe_logits_mfma(const float* __restrict__ x, const _Float16* __restrict__ pk,
                     float* __restrict__ part0, float* __restrict__ part1)
{
    const int lane = threadIdx.x & 63;
    const int wid  = threadIdx.x >> 6;          // 0..3 token sub-group / stage quarter
    const int kh   = blockIdx.x & 1;            // K half
    const int tg   = blockIdx.x >> 1;           // 0..255 token group of 64
    const int row0 = tg * 64 + wid * 16;
    const int g = lane >> 4, r = lane & 15;

    // coalesced x staging base: instr i covers rows i*4+(lane>>4), 16B at col (lane&15)*4
    const float* xg = x + (size_t)(row0 + (lane >> 4)) * H_DIM + kh * KHALF + (lane & 15) * 4;
    // W staging source: this wave's quarter of each per-kstep slice
    const _Float16* wq = pk + (size_t)(kh * 64) * 2048 + wid * 512 + (size_t)lane * 8;

    __shared__ _Float16 sw[2][2][4096];   // [buf][kip][t*2048+nf*512+lane*8] : 32 KB
    __shared__ float    sx[2][4][1088];   // [buf][wave][col*17 + row]        : 34.8 KB
    const int lbase = wid * 512 + lane * 8;
    const int c0 = (lane & 15) * 4;       // staged col group
    const int rq = lane >> 4;             // staged row-in-quad

    f32x4 acc[4], accL[4];
#pragma unroll
    for (int nf = 0; nf < 4; ++nf) { acc[nf] = (f32x4)0.0f; accL[nf] = (f32x4)0.0f; }

    f32x4 xst[2][4];       // [phase-buf][row-quad]
    f16x8 wr[2][2][2];     // [phase-buf][kip][term]  W for phase P+1 in wr[(P+1)&1]

    // ---- prologue: regs <- x/W of phases 0,1; LDS buf0 <- phase 0
#pragma unroll
    for (int i = 0; i < 4; ++i) {
        xst[0][i] = *(const f32x4*)(xg + (size_t)i * 4 * H_DIM);
        xst[1][i] = *(const f32x4*)(xg + (size_t)i * 4 * H_DIM + 64);
    }
#pragma unroll
    for (int kip = 0; kip < 2; ++kip)
#pragma unroll
        for (int t = 0; t < 2; ++t) {
            wr[0][kip][t] = *(const f16x8*)(wq + kip * 2048 + t * WTERM);
            wr[1][kip][t] = *(const f16x8*)(wq + 4096 + kip * 2048 + t * WTERM);
        }
#pragma unroll
    for (int kip = 0; kip < 2; ++kip)
#pragma unroll
        for (int t = 0; t < 2; ++t)
            *(f16x8*)&sw[0][kip][t * 2048 + lbase] = wr[0][kip][t];
#pragma unroll
    for (int i = 0; i < 4; ++i)
#pragma unroll
        for (int j = 0; j < 4; ++j)
            sx[0][wid][(c0 + j) * 17 + i * 4 + rq] = xst[0][i][j];
    asm volatile("s_waitcnt lgkmcnt(0)\n\ts_barrier" ::: "memory");

    // PHASE(b_, DSW_, PFW_, PFX_):
    //  b_: phase parity (LDS/reg buffer), DSW_: ds_write regs of P+1 -> buf b^1
    //  PFW_: issue W(P+2) -> wr[b_];  PFX_: issue x(P+2) -> xst[b_]
#define PHASE(b_, DSW_, PFW_, PFX_)                                            \
    do {                                                                       \
        if (DSW_) {                                                            \
            _Pragma("unroll")                                                  \
            for (int kip = 0; kip < 2; ++kip)                                  \
                _Pragma("unroll")                                              \
                for (int t = 0; t < 2; ++t)                                    \
                    *(f16x8*)&sw[(b_) ^ 1][kip][t * 2048 + lbase] =            \
                        wr[(b_) ^ 1][kip][t];                                  \
            _Pragma("unroll")                                                  \
            for (int i = 0; i < 4; ++i)                                        \
                _Pragma("unroll")                                              \
                for (int j = 0; j < 4; ++j)                                    \
                    sx[(b_) ^ 1][wid][(c0 + j) * 17 + i * 4 + rq] =            \
                        xst[(b_) ^ 1][i][j];                                   \
        }                                                                      \
        if (PFW_) {                                                            \
            _Pragma("unroll")                                                  \
            for (int kip = 0; kip < 2; ++kip)                                  \
                _Pragma("unroll")                                              \
                for (int t = 0; t < 2; ++t)                                    \
                    wr[b_][kip][t] = *(const f16x8*)(wq + (b_) * 4096 + 8192   \
                                                     + kip * 2048 + t * WTERM);\
        }                                                                      \
        if (PFX_) {                                                            \
            _Pragma("unroll")                                                  \
            for (int i = 0; i < 4; ++i)                                        \
                xst[b_][i] = *(const f32x4*)(xg + (size_t)i * 4 * H_DIM        \
                                             + (b_) * 64 + 128);               \
        }                                                                      \
        _Pragma("unroll")                                                      \
        for (int kip = 0; kip < 2; ++kip) {                                    \
            f16x8 wa[2][4];                                                    \
            _Pragma("unroll")                                                  \
            for (int t = 0; t < 2; ++t)                                        \
                _Pragma("unroll")                                              \
                for (int nf = 0; nf < 4; ++nf)                                 \
                    wa[t][nf] = *(const f16x8*)                                \
                        &sw[b_][kip][t * 2048 + nf * 512 + lane * 8];          \
            float xv[8];                                                       \
            _Pragma("unroll")                                                  \
            for (int j = 0; j < 8; ++j)                                        \
                xv[j] = sx[b_][wid][(kip * 32 + g * 8 + j) * 17 + r];          \
            f16x8 a1, a2;                                                      \
            _Pragma("unroll")                                                  \
            for (int j = 0; j < 8; j += 2) {                                   \
                float v0 = xv[j], v1 = xv[j + 1];                              \
                hp16x2 hp = __builtin_amdgcn_cvt_pkrtz(v0, v1);                \
                float r0 = (v0 - (float)hp[0]) * LO_SCALE;                     \
                float r1 = (v1 - (float)hp[1]) * LO_SCALE;                     \
                hp16x2 lp = __builtin_amdgcn_cvt_pkrtz(r0, r1);                \
                a1[j]     = (_Float16)hp[0];                                   \
                a1[j + 1] = (_Float16)hp[1];                                   \
                a2[j]     = (_Float16)lp[0];                                   \
                a2[j + 1] = (_Float16)lp[1];                                   \
            }                                                                  \
            _Pragma("unroll")                                                  \
            for (int nf = 0; nf < 4; ++nf) {                                   \
                acc[nf]  = __builtin_amdgcn_mfma_f32_16x16x32_f16(             \
                               a1, wa[0][nf], acc[nf], 0, 0, 0);               \
                accL[nf] = __builtin_amdgcn_mfma_f32_16x16x32_f16(             \
                               a1, wa[1][nf], accL[nf], 0, 0, 0);              \
                accL[nf] = __builtin_amdgcn_mfma_f32_16x16x32_f16(             \
                               a2, wa[0][nf], accL[nf], 0, 0, 0);              \
            }                                                                  \
        }                                                                      \
        asm volatile("s_waitcnt lgkmcnt(0)\n\ts_barrier" ::: "memory");        \
    } while (0)

    // phases 0..29 (15 pairs), full pipeline
#pragma unroll 1
    for (int it = 0; it < 15; ++it) {
        PHASE(0, 1, 1, 1);
        PHASE(1, 1, 1, 1);
        xg += 128;
        wq += 8192;
    }
    // phase 30: stage phase-31 regs, no more prefetch
    PHASE(0, 1, 0, 0);
    // phase 31: compute only
    PHASE(1, 0, 0, 0);

#undef PHASE

    // store partial tile: D row (token) = g*4+q, col (expert) = nf*16+r
    float* outp = kh == 0 ? part0 : part1;
#pragma unroll
    for (int nf = 0; nf < 4; ++nf)
#pragma unroll
        for (int q = 0; q < 4; ++q) {
            float v = acc[nf][q] + accL[nf][q] * INV_LO_SCALE;
            outp[(size_t)(row0 + g * 4 + q) * NE + nf * 16 + r] = v;
        }
}

// ---------------- router: transposed, shuffle-free ---------------------------
// lane = token; all softmax + top-8 in registers (pure VALU, no cross-lane).
// scores aliases p0, logits aliases p1: each lane reads only its own row fully
// into regs before writing it; rows are lane-exclusive -> race-free.
__global__ __launch_bounds__(64, 1)
void router_kernel(const float* __restrict__ p0, const float* __restrict__ p1,
                   float* __restrict__ scores, float* __restrict__ logits,
                   float* __restrict__ wts, float* __restrict__ inds)
{
    const int token = blockIdx.x * 64 + threadIdx.x;
    const float* r0 = p0 + (size_t)token * NE;
    const float* r1 = p1 + (size_t)token * NE;

    // load + sum partials into 64 regs
    f32x4 l[16];
#pragma unroll
    for (int i = 0; i < 16; ++i) {
        f32x4 a = *(const f32x4*)(r0 + i * 4);
        f32x4 b = *(const f32x4*)(r1 + i * 4);
        l[i] = a + b;
    }
    // write logits
    float* lo = logits + (size_t)token * NE;
#pragma unroll
    for (int i = 0; i < 16; ++i)
        *(f32x4*)(lo + i * 4) = l[i];

    // softmax max
    float m = l[0][0];
#pragma unroll
    for (int i = 0; i < 16; ++i)
        m = fmaxf(m, fmaxf(fmaxf(l[i][0], l[i][1]), fmaxf(l[i][2], l[i][3])));

    // p = exp(l - m) in place; s = sum
    float s = 0.0f;
#pragma unroll
    for (int i = 0; i < 16; ++i) {
#pragma unroll
        for (int j = 0; j < 4; ++j) {
            float p = expf(l[i][j] - m);
            l[i][j] = p;
            s += p;
        }
    }
    // write scores = p * (1/s)  (order-preserving scale)
    const float invs = 1.0f / s;
    float* so = scores + (size_t)token * NE;
#pragma unroll
    for (int i = 0; i < 16; ++i) {
        f32x4 v = l[i] * invs;
        *(f32x4*)(so + i * 4) = v;
    }

    // destructive top-8 extraction on p (selection order == scores order).
    // First-match scan with (idx<0) guard: stable, lower-index tie-break.
    float tv[TOPK];
    int   ti[TOPK];
    float sum8 = 0.0f;
#pragma unroll
    for (int k = 0; k < TOPK; ++k) {
        float m2 = l[0][0];
#pragma unroll
        for (int i = 0; i < 16; ++i)
            m2 = fmaxf(m2, fmaxf(fmaxf(l[i][0], l[i][1]), fmaxf(l[i][2], l[i][3])));
        int idx = -1;
#pragma unroll
        for (int i = 0; i < 16; ++i) {
#pragma unroll
            for (int j = 0; j < 4; ++j) {
                bool take = (idx < 0) && (l[i][j] == m2);
                idx = take ? (i * 4 + j) : idx;
                l[i][j] = take ? -1.0f : l[i][j];   // p > 0, never re-selected
            }
        }
        tv[k] = m2; ti[k] = idx;
        sum8 += m2;
    }

    // weights: p_k / sum(p_top8)  == ref's L1-renorm of scores exactly
    const float inv8 = 1.0f / sum8;
    float* wo = wts  + (size_t)token * TOPK;
    float* io = inds + (size_t)token * TOPK;
#pragma unroll
    for (int h = 0; h < 2; ++h) {
        f32x4 wv, iv;
#pragma unroll
        for (int j = 0; j < 4; ++j) {
            wv[j] = tv[h * 4 + j] * inv8;
            iv[j] = (float)ti[h * 4 + j];
        }
        *(f32x4*)(wo + h * 4) = wv;
        *(f32x4*)(io + h * 4) = iv;
    }
}

extern "C" void kernel_launch(void* const* d_in, const int* in_sizes, int n_in,
                              void* d_out, int out_size, void* d_ws, size_t ws_size,
                              hipStream_t stream)
{
    const float* x = (const float*)d_in[0];
    const float* W = (const float*)d_in[1];
    const int N = in_sizes[0] / H_DIM;   // 16384

    float* out    = (float*)d_out;
    float* scores = out;                          // [N,64]  (doubles as partial kh=0)
    float* logits = out + (size_t)N * NE;         // [N,64]  (doubles as partial kh=1)
    float* wts    = out + (size_t)2 * N * NE;     // [N,8]
    float* inds   = wts + (size_t)N * TOPK;       // [N,8] as float

    _Float16* pk = (_Float16*)d_ws;               // 2 * 262144 * 2B = 1 MB

    pack_w_kernel<<<(NE * H_DIM) / 256, 256, 0, stream>>>(W, pk);
    moe_logits_mfma<<<(N / 64) * 2, 256, 0, stream>>>(x, pk, scores, logits);
    router_kernel<<<N / 64, 64, 0, stream>>>(scores, logits, scores, logits,
                                             wts, inds);
}